// Round 1
// baseline (1379.814 us; speedup 1.0000x reference)
//
#include <hip/hip_runtime.h>
#include <math.h>

#define N_NODES 50000
#define N_EDGES 200000
#define NEG_SLOPE 0.2f
#define BN_EPS 1e-5f

// ---------------- CSR build ----------------
__global__ void k_init(int* cnt, int* off) {
    int i = blockIdx.x * blockDim.x + threadIdx.x;
    if (i < N_NODES) { cnt[i] = 1; off[i] = 1; }  // slot 0 reserved for self-loop
}

__global__ void k_count(const int* __restrict__ ei, int* cnt) {
    int e = blockIdx.x * blockDim.x + threadIdx.x;
    if (e < N_EDGES) atomicAdd(&cnt[ei[N_EDGES + e]], 1);
}

// single-block exclusive scan over 50000 counts -> row_ptr[0..N]
__global__ void k_scan(const int* __restrict__ cnt, int* row_ptr) {
    __shared__ int sh[1024];
    __shared__ int carry_sh;
    if (threadIdx.x == 0) { carry_sh = 0; row_ptr[0] = 0; }
    __syncthreads();
    for (int base = 0; base < N_NODES; base += 1024) {
        int i = base + (int)threadIdx.x;
        int v = (i < N_NODES) ? cnt[i] : 0;
        sh[threadIdx.x] = v;
        __syncthreads();
        for (int off = 1; off < 1024; off <<= 1) {
            int t = (threadIdx.x >= (unsigned)off) ? sh[threadIdx.x - off] : 0;
            __syncthreads();
            sh[threadIdx.x] += t;
            __syncthreads();
        }
        int inc = sh[threadIdx.x] + carry_sh;
        if (i < N_NODES) row_ptr[i + 1] = inc;
        __syncthreads();
        if (threadIdx.x == 1023) carry_sh = inc;
        __syncthreads();
    }
}

__global__ void k_self(const int* __restrict__ row_ptr, int* colb) {
    int n = blockIdx.x * blockDim.x + threadIdx.x;
    if (n < N_NODES) colb[row_ptr[n]] = n;
}

__global__ void k_scatter(const int* __restrict__ ei, const int* __restrict__ row_ptr,
                          int* off, int* colb) {
    int e = blockIdx.x * blockDim.x + threadIdx.x;
    if (e < N_EDGES) {
        int dst = ei[N_EDGES + e];
        int p = atomicAdd(&off[dst], 1);
        colb[row_ptr[dst] + p] = ei[e];
    }
}

// ---------------- f32 GEMM: C[M,Nc] = A[M,K] @ B[K,Nc] ----------------
// 64x64 tile, 256 threads, 4x4 micro-tile, BK=32.
__global__ __launch_bounds__(256) void k_gemm(const float* __restrict__ A,
                                              const float* __restrict__ B,
                                              float* __restrict__ C,
                                              int M, int K, int Nc) {
    __shared__ float As[32][64];
    __shared__ float Bs[32][64];
    const int tid = threadIdx.x;
    const int tr = tid >> 4, tc = tid & 15;
    const int row0 = blockIdx.x * 64, col0 = blockIdx.y * 64;
    float acc[4][4] = {};
    for (int k0 = 0; k0 < K; k0 += 32) {
#pragma unroll
        for (int l = 0; l < 2; ++l) {
            int f = tid + l * 256;
            int r = f >> 3, c4 = (f & 7) << 2;
            float4 v = make_float4(0.f, 0.f, 0.f, 0.f);
            if (row0 + r < M)
                v = *reinterpret_cast<const float4*>(&A[(size_t)(row0 + r) * K + k0 + c4]);
            As[c4 + 0][r] = v.x; As[c4 + 1][r] = v.y;
            As[c4 + 2][r] = v.z; As[c4 + 3][r] = v.w;
        }
#pragma unroll
        for (int l = 0; l < 2; ++l) {
            int f = tid + l * 256;
            int r = f >> 4, c4 = (f & 15) << 2;
            float4 v = *reinterpret_cast<const float4*>(&B[(size_t)(k0 + r) * Nc + col0 + c4]);
            *reinterpret_cast<float4*>(&Bs[r][c4]) = v;
        }
        __syncthreads();
#pragma unroll
        for (int k = 0; k < 32; ++k) {
            float4 a = *reinterpret_cast<const float4*>(&As[k][tr << 2]);
            float4 b = *reinterpret_cast<const float4*>(&Bs[k][tc << 2]);
            float av[4] = {a.x, a.y, a.z, a.w};
            float bv[4] = {b.x, b.y, b.z, b.w};
#pragma unroll
            for (int i = 0; i < 4; ++i)
#pragma unroll
                for (int j = 0; j < 4; ++j)
                    acc[i][j] = fmaf(av[i], bv[j], acc[i][j]);
        }
        __syncthreads();
    }
#pragma unroll
    for (int i = 0; i < 4; ++i) {
        int r = row0 + (tr << 2) + i;
        if (r < M) {
            float4 v = make_float4(acc[i][0], acc[i][1], acc[i][2], acc[i][3]);
            *reinterpret_cast<float4*>(&C[(size_t)r * Nc + col0 + (tc << 2)]) = v;
        }
    }
}

// ---------------- per-(node,head) attention scores ----------------
template <int H>
__global__ void k_scores(const float* __restrict__ xp, const float* __restrict__ asrc,
                         const float* __restrict__ adst, float* __restrict__ es,
                         float* __restrict__ ed) {
    const int n = blockIdx.x;
    const int w = threadIdx.x >> 6;  // head
    const int lane = threadIdx.x & 63;
    const float* xr = xp + (size_t)n * H * 128 + w * 128;
    float v0 = xr[lane], v1 = xr[lane + 64];
    float ps = v0 * asrc[w * 128 + lane] + v1 * asrc[w * 128 + lane + 64];
    float pd = v0 * adst[w * 128 + lane] + v1 * adst[w * 128 + lane + 64];
#pragma unroll
    for (int o = 32; o > 0; o >>= 1) {
        ps += __shfl_down(ps, o);
        pd += __shfl_down(pd, o);
    }
    if (lane == 0) { es[n * H + w] = ps; ed[n * H + w] = pd; }
}

// ---------------- per-node softmax aggregation + bias + BN + ReLU ----------------
template <int H, int C, int BLK>
__global__ __launch_bounds__(BLK) void k_agg(
    const float* __restrict__ xp, const float* __restrict__ es, const float* __restrict__ ed,
    const int* __restrict__ row_ptr, const int* __restrict__ colb,
    const float* __restrict__ bias, const float* __restrict__ gg, const float* __restrict__ be,
    const float* __restrict__ mu, const float* __restrict__ var, float* __restrict__ out) {
    constexpr int HC = H * C;
    constexpr int CPT = HC / BLK;
    constexpr int CHUNK = 128;
    __shared__ int s_src[CHUNK];
    __shared__ float s_w[CHUNK][H];
    __shared__ float s_scale[H];
    __shared__ float s_sum[H];
    const int n = blockIdx.x;
    const int tid = threadIdx.x;
    const int beg = row_ptr[n], end = row_ptr[n + 1];
    float acc[CPT];
#pragma unroll
    for (int j = 0; j < CPT; ++j) acc[j] = 0.f;
    float m_run = -INFINITY, s_run = 0.f;  // live only in tid < H
    for (int cbeg = beg; cbeg < end; cbeg += CHUNK) {
        const int cnt = min(end - cbeg, CHUNK);
        for (int i = tid; i < cnt; i += BLK) {
            int src = colb[cbeg + i];
            s_src[i] = src;
#pragma unroll
            for (int h = 0; h < H; ++h) {
                float e = es[src * H + h] + ed[n * H + h];
                s_w[i][h] = (e > 0.f) ? e : NEG_SLOPE * e;
            }
        }
        __syncthreads();
        if (tid < H) {
            const int h = tid;
            float cm = -INFINITY;
            for (int i = 0; i < cnt; ++i) cm = fmaxf(cm, s_w[i][h]);
            float m_new = fmaxf(m_run, cm);
            float scale = __expf(m_run - m_new);  // 0 on first chunk
            float s = s_run * scale;
            for (int i = 0; i < cnt; ++i) {
                float w = __expf(s_w[i][h] - m_new);
                s_w[i][h] = w;
                s += w;
            }
            s_run = s; m_run = m_new;
            s_scale[h] = scale;
            s_sum[h] = s;
        }
        __syncthreads();
#pragma unroll
        for (int j = 0; j < CPT; ++j) {
            int ch = tid + j * BLK;
            int h = ch / C;
            float a = acc[j] * s_scale[h];
            for (int i = 0; i < cnt; ++i)
                a = fmaf(s_w[i][h], xp[(size_t)s_src[i] * HC + ch], a);
            acc[j] = a;
        }
        __syncthreads();
    }
#pragma unroll
    for (int j = 0; j < CPT; ++j) {
        int ch = tid + j * BLK;
        int h = ch / C;
        float val = acc[j] / (s_sum[h] + 1e-16f) + bias[ch];
        float sc = gg[ch] * rsqrtf(var[ch] + BN_EPS);
        val = (val - mu[ch]) * sc + be[ch];
        out[(size_t)n * HC + ch] = fmaxf(val, 0.f);
    }
}

// ---------------- classifier head + softmax ----------------
__global__ __launch_bounds__(64) void k_cls(const float* __restrict__ Eg,
                                            const float* __restrict__ Wc1,
                                            const float* __restrict__ bc1,
                                            const float* __restrict__ Wc2,
                                            const float* __restrict__ bc2,
                                            float* __restrict__ P) {
    __shared__ float e_sh[128];
    __shared__ float h_sh[64];
    __shared__ float l_sh[10];
    const int n = blockIdx.x;
    const int t = threadIdx.x;
    e_sh[t] = Eg[(size_t)n * 128 + t];
    e_sh[t + 64] = Eg[(size_t)n * 128 + 64 + t];
    __syncthreads();
    float a = bc1[t];
#pragma unroll 4
    for (int k = 0; k < 128; ++k) a = fmaf(e_sh[k], Wc1[k * 64 + t], a);
    h_sh[t] = fmaxf(a, 0.f);
    __syncthreads();
    if (t < 10) {
        float b = bc2[t];
#pragma unroll 8
        for (int k = 0; k < 64; ++k) b = fmaf(h_sh[k], Wc2[k * 10 + t], b);
        l_sh[t] = b;
    }
    __syncthreads();
    if (t == 0) {
        float mx = l_sh[0];
        for (int j = 1; j < 10; ++j) mx = fmaxf(mx, l_sh[j]);
        float s = 0.f;
        float ex[10];
        for (int j = 0; j < 10; ++j) { ex[j] = __expf(l_sh[j] - mx); s += ex[j]; }
        float inv = 1.f / s;
        for (int j = 0; j < 10; ++j) P[(size_t)n * 10 + j] = ex[j] * inv;
    }
}

extern "C" void kernel_launch(void* const* d_in, const int* in_sizes, int n_in,
                              void* d_out, int out_size, void* d_ws, size_t ws_size,
                              hipStream_t stream) {
    const float* x     = (const float*)d_in[0];
    const int*   ei    = (const int*)d_in[1];
    const float* W1    = (const float*)d_in[2];
    const float* asrc1 = (const float*)d_in[3];
    const float* adst1 = (const float*)d_in[4];
    const float* b1    = (const float*)d_in[5];
    const float* gg1   = (const float*)d_in[6];
    const float* be1   = (const float*)d_in[7];
    const float* mu1   = (const float*)d_in[8];
    const float* v1    = (const float*)d_in[9];
    const float* W2    = (const float*)d_in[10];
    const float* asrc2 = (const float*)d_in[11];
    const float* adst2 = (const float*)d_in[12];
    const float* b2    = (const float*)d_in[13];
    const float* gg2   = (const float*)d_in[14];
    const float* be2   = (const float*)d_in[15];
    const float* mu2   = (const float*)d_in[16];
    const float* v2    = (const float*)d_in[17];
    const float* W3    = (const float*)d_in[18];
    const float* asrc3 = (const float*)d_in[19];
    const float* adst3 = (const float*)d_in[20];
    const float* b3    = (const float*)d_in[21];
    const float* gg3   = (const float*)d_in[22];
    const float* be3   = (const float*)d_in[23];
    const float* mu3   = (const float*)d_in[24];
    const float* v3    = (const float*)d_in[25];
    const float* Wc1   = (const float*)d_in[26];
    const float* bc1   = (const float*)d_in[27];
    const float* Wc2   = (const float*)d_in[28];
    const float* bc2   = (const float*)d_in[29];

    // workspace layout (~208 MB)
    float* bufA = (float*)d_ws;                  // xp buffer, N*512
    float* bufB = bufA + (size_t)N_NODES * 512;  // h buffer, N*512
    float* es   = bufB + (size_t)N_NODES * 512;
    float* ed   = es + (size_t)N_NODES * 4;
    int* cnt    = (int*)(ed + (size_t)N_NODES * 4);
    int* off    = cnt + N_NODES;
    int* row_ptr = off + N_NODES;
    int* colb   = row_ptr + N_NODES + 4;

    float* Egnn = (float*)d_out;
    float* P    = Egnn + (size_t)N_NODES * 128;

    // ---- CSR build ----
    k_init<<<(N_NODES + 255) / 256, 256, 0, stream>>>(cnt, off);
    k_count<<<(N_EDGES + 255) / 256, 256, 0, stream>>>(ei, cnt);
    k_scan<<<1, 1024, 0, stream>>>(cnt, row_ptr);
    k_self<<<(N_NODES + 255) / 256, 256, 0, stream>>>(row_ptr, colb);
    k_scatter<<<(N_EDGES + 255) / 256, 256, 0, stream>>>(ei, row_ptr, off, colb);

    const int mt = (N_NODES + 63) / 64;  // 782

    // ---- layer 1: 256 -> 4x128 ----
    {
        dim3 grid(mt, 8);
        k_gemm<<<grid, 256, 0, stream>>>(x, W1, bufA, N_NODES, 256, 512);
    }
    k_scores<4><<<N_NODES, 256, 0, stream>>>(bufA, asrc1, adst1, es, ed);
    k_agg<4, 128, 256><<<N_NODES, 256, 0, stream>>>(bufA, es, ed, row_ptr, colb,
                                                    b1, gg1, be1, mu1, v1, bufB);
    // ---- layer 2: 512 -> 4x128 ----
    {
        dim3 grid(mt, 8);
        k_gemm<<<grid, 256, 0, stream>>>(bufB, W2, bufA, N_NODES, 512, 512);
    }
    k_scores<4><<<N_NODES, 256, 0, stream>>>(bufA, asrc2, adst2, es, ed);
    k_agg<4, 128, 256><<<N_NODES, 256, 0, stream>>>(bufA, es, ed, row_ptr, colb,
                                                    b2, gg2, be2, mu2, v2, bufB);
    // ---- layer 3: 512 -> 1x128 ----
    {
        dim3 grid(mt, 2);
        k_gemm<<<grid, 256, 0, stream>>>(bufB, W3, bufA, N_NODES, 512, 128);
    }
    k_scores<1><<<N_NODES, 64, 0, stream>>>(bufA, asrc3, adst3, es, ed);
    k_agg<1, 128, 128><<<N_NODES, 128, 0, stream>>>(bufA, es, ed, row_ptr, colb,
                                                    b3, gg3, be3, mu3, v3, Egnn);
    // ---- classifier ----
    k_cls<<<N_NODES, 64, 0, stream>>>(Egnn, Wc1, bc1, Wc2, bc2, P);
}

// Round 2
// 874.707 us; speedup vs baseline: 1.5775x; 1.5775x over previous
//
#include <hip/hip_runtime.h>
#include <math.h>

#define N_NODES 50000
#define N_EDGES 200000
#define NEG_SLOPE 0.2f
#define BN_EPS 1e-5f

typedef __attribute__((ext_vector_type(4))) float f32x4;
typedef __attribute__((ext_vector_type(8))) short bf16x8;

__device__ __forceinline__ ushort f2bf(float x) {
    unsigned u = __float_as_uint(x);
    u += 0x7FFFu + ((u >> 16) & 1u);
    return (ushort)(u >> 16);
}

// ---------------- CSR build ----------------
__global__ void k_init(int* cnt, int* off) {
    int i = blockIdx.x * blockDim.x + threadIdx.x;
    if (i < N_NODES) { cnt[i] = 1; off[i] = 1; }  // slot 0 reserved for self-loop
}

__global__ void k_count(const int* __restrict__ ei, int* cnt) {
    int e = blockIdx.x * blockDim.x + threadIdx.x;
    if (e < N_EDGES) atomicAdd(&cnt[ei[N_EDGES + e]], 1);
}

__global__ void k_scan(const int* __restrict__ cnt, int* row_ptr) {
    __shared__ int sh[1024];
    __shared__ int carry_sh;
    if (threadIdx.x == 0) { carry_sh = 0; row_ptr[0] = 0; }
    __syncthreads();
    for (int base = 0; base < N_NODES; base += 1024) {
        int i = base + (int)threadIdx.x;
        int v = (i < N_NODES) ? cnt[i] : 0;
        sh[threadIdx.x] = v;
        __syncthreads();
        for (int off = 1; off < 1024; off <<= 1) {
            int t = (threadIdx.x >= (unsigned)off) ? sh[threadIdx.x - off] : 0;
            __syncthreads();
            sh[threadIdx.x] += t;
            __syncthreads();
        }
        int inc = sh[threadIdx.x] + carry_sh;
        if (i < N_NODES) row_ptr[i + 1] = inc;
        __syncthreads();
        if (threadIdx.x == 1023) carry_sh = inc;
        __syncthreads();
    }
}

__global__ void k_self(const int* __restrict__ row_ptr, int* colb) {
    int n = blockIdx.x * blockDim.x + threadIdx.x;
    if (n < N_NODES) colb[row_ptr[n]] = n;
}

__global__ void k_scatter(const int* __restrict__ ei, const int* __restrict__ row_ptr,
                          int* off, int* colb) {
    int e = blockIdx.x * blockDim.x + threadIdx.x;
    if (e < N_EDGES) {
        int dst = ei[N_EDGES + e];
        int p = atomicAdd(&off[dst], 1);
        colb[row_ptr[dst] + p] = ei[e];
    }
}

// ---------------- f32 -> bf16 convert (vector) ----------------
__global__ void k_cvt(const float* __restrict__ in, ushort* __restrict__ out, int n4) {
    int i = blockIdx.x * blockDim.x + threadIdx.x;
    if (i < n4) {
        float4 v = reinterpret_cast<const float4*>(in)[i];
        ushort4 o;
        o.x = f2bf(v.x); o.y = f2bf(v.y); o.z = f2bf(v.z); o.w = f2bf(v.w);
        reinterpret_cast<ushort4*>(out)[i] = o;
    }
}

// ---------------- W[K][N] -> Wt[N][K] bf16 transpose-convert ----------------
__global__ void k_wt(const float* __restrict__ W, ushort* __restrict__ Wt, int K, int N) {
    int idx = blockIdx.x * blockDim.x + threadIdx.x;
    if (idx < K * N) {
        int n = idx / K, k = idx - n * K;
        Wt[idx] = f2bf(W[(size_t)k * N + n]);
    }
}

// ---------------- bf16 MFMA GEMM: C[M,N] = A[M,K] @ Bt[N,K]^T ----------------
// 128x128 tile, 4 waves (2x2), BK=32, global_load_lds staging (m97 structure).
__global__ __launch_bounds__(256) void k_gemm_bf16(const ushort* __restrict__ A,
                                                   const ushort* __restrict__ Bt,
                                                   float* __restrict__ C,
                                                   int M, int K, int N) {
    __shared__ __align__(16) ushort As[128 * 32];
    __shared__ __align__(16) ushort Bs[128 * 32];
    const int tid = threadIdx.x;
    const int wid = tid >> 6, lane = tid & 63;
    const int wm = wid >> 1, wn = wid & 1;
    const int row0 = blockIdx.x * 128, col0 = blockIdx.y * 128;

    // staging geometry: 16 chunks of 1024B per tile; wave w owns chunks {2w, 2w+1}
    const int c0 = wid * 2;
    const int sub = lane >> 2;        // 0..15: row within chunk
    const int kcol = (lane & 3) * 8;  // element column within 32-wide K slab

    int ar0 = row0 + c0 * 16 + sub;      if (ar0 > M - 1) ar0 = M - 1;
    int ar1 = row0 + c0 * 16 + 16 + sub; if (ar1 > M - 1) ar1 = M - 1;
    const size_t gA0 = (size_t)ar0 * K + kcol;
    const size_t gA1 = (size_t)ar1 * K + kcol;
    const size_t gB0 = (size_t)(col0 + c0 * 16 + sub) * K + kcol;
    const size_t gB1 = gB0 + (size_t)16 * K;
    ushort* lA0 = As + c0 * 512;
    ushort* lA1 = lA0 + 512;
    ushort* lB0 = Bs + c0 * 512;
    ushort* lB1 = lB0 + 512;

    // fragment read offsets (elements)
    const int afr = (wm * 64 + (lane & 15)) * 32 + (lane >> 4) * 8;
    const int bfr = (wn * 64 + (lane & 15)) * 32 + (lane >> 4) * 8;

    f32x4 acc[4][4] = {};

    for (int k0 = 0; k0 < K; k0 += 32) {
        __builtin_amdgcn_global_load_lds(
            (const __attribute__((address_space(1))) unsigned*)(A + gA0 + k0),
            (__attribute__((address_space(3))) unsigned*)lA0, 16, 0, 0);
        __builtin_amdgcn_global_load_lds(
            (const __attribute__((address_space(1))) unsigned*)(A + gA1 + k0),
            (__attribute__((address_space(3))) unsigned*)lA1, 16, 0, 0);
        __builtin_amdgcn_global_load_lds(
            (const __attribute__((address_space(1))) unsigned*)(Bt + gB0 + k0),
            (__attribute__((address_space(3))) unsigned*)lB0, 16, 0, 0);
        __builtin_amdgcn_global_load_lds(
            (const __attribute__((address_space(1))) unsigned*)(Bt + gB1 + k0),
            (__attribute__((address_space(3))) unsigned*)lB1, 16, 0, 0);
        __syncthreads();  // compiler drains vmcnt before s_barrier

        bf16x8 af[4], bg[4];
#pragma unroll
        for (int m = 0; m < 4; ++m)
            af[m] = *reinterpret_cast<const bf16x8*>(&As[afr + m * 16 * 32]);
#pragma unroll
        for (int n = 0; n < 4; ++n)
            bg[n] = *reinterpret_cast<const bf16x8*>(&Bs[bfr + n * 16 * 32]);
#pragma unroll
        for (int m = 0; m < 4; ++m)
#pragma unroll
            for (int n = 0; n < 4; ++n)
                acc[m][n] = __builtin_amdgcn_mfma_f32_16x16x32_bf16(af[m], bg[n], acc[m][n], 0, 0, 0);
        __syncthreads();
    }

    const int crow = row0 + wm * 64 + (lane >> 4) * 4;
    const int ccol = col0 + wn * 64 + (lane & 15);
#pragma unroll
    for (int m = 0; m < 4; ++m) {
#pragma unroll
        for (int j = 0; j < 4; ++j) {
            int r = crow + m * 16 + j;
            if (r < M) {
#pragma unroll
                for (int n = 0; n < 4; ++n)
                    C[(size_t)r * N + ccol + n * 16] = acc[m][n][j];
            }
        }
    }
}

// ---------------- per-(node,head) attention scores ----------------
template <int H>
__global__ void k_scores(const float* __restrict__ xp, const float* __restrict__ asrc,
                         const float* __restrict__ adst, float* __restrict__ es,
                         float* __restrict__ ed) {
    const int n = blockIdx.x;
    const int w = threadIdx.x >> 6;  // head
    const int lane = threadIdx.x & 63;
    const float* xr = xp + (size_t)n * H * 128 + w * 128;
    float v0 = xr[lane], v1 = xr[lane + 64];
    float ps = v0 * asrc[w * 128 + lane] + v1 * asrc[w * 128 + lane + 64];
    float pd = v0 * adst[w * 128 + lane] + v1 * adst[w * 128 + lane + 64];
#pragma unroll
    for (int o = 32; o > 0; o >>= 1) {
        ps += __shfl_down(ps, o);
        pd += __shfl_down(pd, o);
    }
    if (lane == 0) { es[n * H + w] = ps; ed[n * H + w] = pd; }
}

// ---------------- per-node softmax aggregation + bias + BN + ReLU ----------------
template <int H, int C, int BLK, bool BF16OUT>
__global__ __launch_bounds__(BLK) void k_agg(
    const float* __restrict__ xp, const float* __restrict__ es, const float* __restrict__ ed,
    const int* __restrict__ row_ptr, const int* __restrict__ colb,
    const float* __restrict__ bias, const float* __restrict__ gg, const float* __restrict__ be,
    const float* __restrict__ mu, const float* __restrict__ var, void* __restrict__ outv) {
    constexpr int HC = H * C;
    constexpr int CPT = HC / BLK;
    constexpr int CHUNK = 128;
    __shared__ int s_src[CHUNK];
    __shared__ float s_w[CHUNK][H];
    __shared__ float s_scale[H];
    __shared__ float s_sum[H];
    const int n = blockIdx.x;
    const int tid = threadIdx.x;
    const int beg = row_ptr[n], end = row_ptr[n + 1];
    float acc[CPT];
#pragma unroll
    for (int j = 0; j < CPT; ++j) acc[j] = 0.f;
    float m_run = -INFINITY, s_run = 0.f;  // live only in tid < H
    for (int cbeg = beg; cbeg < end; cbeg += CHUNK) {
        const int cnt = min(end - cbeg, CHUNK);
        for (int i = tid; i < cnt; i += BLK) {
            int src = colb[cbeg + i];
            s_src[i] = src;
#pragma unroll
            for (int h = 0; h < H; ++h) {
                float e = es[src * H + h] + ed[n * H + h];
                s_w[i][h] = (e > 0.f) ? e : NEG_SLOPE * e;
            }
        }
        __syncthreads();
        if (tid < H) {
            const int h = tid;
            float cm = -INFINITY;
            for (int i = 0; i < cnt; ++i) cm = fmaxf(cm, s_w[i][h]);
            float m_new = fmaxf(m_run, cm);
            float scale = __expf(m_run - m_new);
            float s = s_run * scale;
            for (int i = 0; i < cnt; ++i) {
                float w = __expf(s_w[i][h] - m_new);
                s_w[i][h] = w;
                s += w;
            }
            s_run = s; m_run = m_new;
            s_scale[h] = scale;
            s_sum[h] = s;
        }
        __syncthreads();
#pragma unroll
        for (int j = 0; j < CPT; ++j) {
            int ch = tid + j * BLK;
            int h = ch / C;
            float a = acc[j] * s_scale[h];
            for (int i = 0; i < cnt; ++i)
                a = fmaf(s_w[i][h], xp[(size_t)s_src[i] * HC + ch], a);
            acc[j] = a;
        }
        __syncthreads();
    }
#pragma unroll
    for (int j = 0; j < CPT; ++j) {
        int ch = tid + j * BLK;
        int h = ch / C;
        float val = acc[j] / (s_sum[h] + 1e-16f) + bias[ch];
        float sc = gg[ch] * rsqrtf(var[ch] + BN_EPS);
        val = (val - mu[ch]) * sc + be[ch];
        val = fmaxf(val, 0.f);
        if (BF16OUT)
            ((ushort*)outv)[(size_t)n * HC + ch] = f2bf(val);
        else
            ((float*)outv)[(size_t)n * HC + ch] = val;
    }
}

// ---------------- classifier head + softmax ----------------
__global__ __launch_bounds__(64) void k_cls(const float* __restrict__ Eg,
                                            const float* __restrict__ Wc1,
                                            const float* __restrict__ bc1,
                                            const float* __restrict__ Wc2,
                                            const float* __restrict__ bc2,
                                            float* __restrict__ P) {
    __shared__ float e_sh[128];
    __shared__ float h_sh[64];
    __shared__ float l_sh[10];
    const int n = blockIdx.x;
    const int t = threadIdx.x;
    e_sh[t] = Eg[(size_t)n * 128 + t];
    e_sh[t + 64] = Eg[(size_t)n * 128 + 64 + t];
    __syncthreads();
    float a = bc1[t];
#pragma unroll 4
    for (int k = 0; k < 128; ++k) a = fmaf(e_sh[k], Wc1[k * 64 + t], a);
    h_sh[t] = fmaxf(a, 0.f);
    __syncthreads();
    if (t < 10) {
        float b = bc2[t];
#pragma unroll 8
        for (int k = 0; k < 64; ++k) b = fmaf(h_sh[k], Wc2[k * 10 + t], b);
        l_sh[t] = b;
    }
    __syncthreads();
    if (t == 0) {
        float mx = l_sh[0];
        for (int j = 1; j < 10; ++j) mx = fmaxf(mx, l_sh[j]);
        float s = 0.f;
        float ex[10];
        for (int j = 0; j < 10; ++j) { ex[j] = __expf(l_sh[j] - mx); s += ex[j]; }
        float inv = 1.f / s;
        for (int j = 0; j < 10; ++j) P[(size_t)n * 10 + j] = ex[j] * inv;
    }
}

extern "C" void kernel_launch(void* const* d_in, const int* in_sizes, int n_in,
                              void* d_out, int out_size, void* d_ws, size_t ws_size,
                              hipStream_t stream) {
    const float* x     = (const float*)d_in[0];
    const int*   ei    = (const int*)d_in[1];
    const float* W1    = (const float*)d_in[2];
    const float* asrc1 = (const float*)d_in[3];
    const float* adst1 = (const float*)d_in[4];
    const float* b1    = (const float*)d_in[5];
    const float* gg1   = (const float*)d_in[6];
    const float* be1   = (const float*)d_in[7];
    const float* mu1   = (const float*)d_in[8];
    const float* v1    = (const float*)d_in[9];
    const float* W2    = (const float*)d_in[10];
    const float* asrc2 = (const float*)d_in[11];
    const float* adst2 = (const float*)d_in[12];
    const float* b2    = (const float*)d_in[13];
    const float* gg2   = (const float*)d_in[14];
    const float* be2   = (const float*)d_in[15];
    const float* mu2   = (const float*)d_in[16];
    const float* v2    = (const float*)d_in[17];
    const float* W3    = (const float*)d_in[18];
    const float* asrc3 = (const float*)d_in[19];
    const float* adst3 = (const float*)d_in[20];
    const float* b3    = (const float*)d_in[21];
    const float* gg3   = (const float*)d_in[22];
    const float* be3   = (const float*)d_in[23];
    const float* mu3   = (const float*)d_in[24];
    const float* v3    = (const float*)d_in[25];
    const float* Wc1   = (const float*)d_in[26];
    const float* bc1   = (const float*)d_in[27];
    const float* Wc2   = (const float*)d_in[28];
    const float* bc2   = (const float*)d_in[29];

    // ---- workspace layout (~158 MB) ----
    float*  bufA = (float*)d_ws;                       // xp f32, N*512
    ushort* hh   = (ushort*)(bufA + (size_t)N_NODES * 512);  // bf16 GEMM input, N*512
    ushort* wt1  = hh + (size_t)N_NODES * 512;         // 512*256
    ushort* wt2  = wt1 + 512 * 256;                    // 512*512
    ushort* wt3  = wt2 + 512 * 512;                    // 128*512
    float*  es   = (float*)(wt3 + 128 * 512);
    float*  ed   = es + (size_t)N_NODES * 4;
    int* cnt     = (int*)(ed + (size_t)N_NODES * 4);
    int* off     = cnt + N_NODES;
    int* row_ptr = off + N_NODES;
    int* colb    = row_ptr + N_NODES + 4;

    float* Egnn = (float*)d_out;
    float* P    = Egnn + (size_t)N_NODES * 128;

    // ---- CSR build ----
    k_init<<<(N_NODES + 255) / 256, 256, 0, stream>>>(cnt, off);
    k_count<<<(N_EDGES + 255) / 256, 256, 0, stream>>>(ei, cnt);
    k_scan<<<1, 1024, 0, stream>>>(cnt, row_ptr);
    k_self<<<(N_NODES + 255) / 256, 256, 0, stream>>>(row_ptr, colb);
    k_scatter<<<(N_EDGES + 255) / 256, 256, 0, stream>>>(ei, row_ptr, off, colb);

    // ---- weight transpose-converts + x convert ----
    k_wt<<<(512 * 256 + 255) / 256, 256, 0, stream>>>(W1, wt1, 256, 512);
    k_wt<<<(512 * 512 + 255) / 256, 256, 0, stream>>>(W2, wt2, 512, 512);
    k_wt<<<(128 * 512 + 255) / 256, 256, 0, stream>>>(W3, wt3, 512, 128);
    {
        int n4 = N_NODES * 256 / 4;
        k_cvt<<<(n4 + 255) / 256, 256, 0, stream>>>(x, hh, n4);
    }

    const int mt = (N_NODES + 127) / 128;  // 391

    // ---- layer 1: 256 -> 4x128 ----
    {
        dim3 grid(mt, 4);
        k_gemm_bf16<<<grid, 256, 0, stream>>>(hh, wt1, bufA, N_NODES, 256, 512);
    }
    k_scores<4><<<N_NODES, 256, 0, stream>>>(bufA, asrc1, adst1, es, ed);
    k_agg<4, 128, 256, true><<<N_NODES, 256, 0, stream>>>(bufA, es, ed, row_ptr, colb,
                                                          b1, gg1, be1, mu1, v1, hh);
    // ---- layer 2: 512 -> 4x128 ----
    {
        dim3 grid(mt, 4);
        k_gemm_bf16<<<grid, 256, 0, stream>>>(hh, wt2, bufA, N_NODES, 512, 512);
    }
    k_scores<4><<<N_NODES, 256, 0, stream>>>(bufA, asrc2, adst2, es, ed);
    k_agg<4, 128, 256, true><<<N_NODES, 256, 0, stream>>>(bufA, es, ed, row_ptr, colb,
                                                          b2, gg2, be2, mu2, v2, hh);
    // ---- layer 3: 512 -> 1x128 ----
    {
        dim3 grid(mt, 1);
        k_gemm_bf16<<<grid, 256, 0, stream>>>(hh, wt3, bufA, N_NODES, 512, 128);
    }
    k_scores<1><<<N_NODES, 64, 0, stream>>>(bufA, asrc3, adst3, es, ed);
    k_agg<1, 128, 128, false><<<N_NODES, 128, 0, stream>>>(bufA, es, ed, row_ptr, colb,
                                                           b3, gg3, be3, mu3, v3, Egnn);
    // ---- classifier ----
    k_cls<<<N_NODES, 64, 0, stream>>>(Egnn, Wc1, bc1, Wc2, bc2, P);
}

// Round 3
// 682.905 us; speedup vs baseline: 2.0205x; 1.2809x over previous
//
#include <hip/hip_runtime.h>
#include <math.h>

#define N_NODES 50000
#define N_EDGES 200000
#define NEG_SLOPE 0.2f
#define BN_EPS 1e-5f

typedef __attribute__((ext_vector_type(4))) float f32x4;
typedef __attribute__((ext_vector_type(8))) short bf16x8;

__device__ __forceinline__ ushort f2bf(float x) {
    unsigned u = __float_as_uint(x);
    u += 0x7FFFu + ((u >> 16) & 1u);
    return (ushort)(u >> 16);
}
__device__ __forceinline__ float bf2f(ushort u) {
    return __uint_as_float(((unsigned)u) << 16);
}

// ---------------- CSR build ----------------
__global__ void k_init(int* cnt, int* off) {
    int i = blockIdx.x * blockDim.x + threadIdx.x;
    if (i < N_NODES) { cnt[i] = 1; off[i] = 1; }  // slot 0 reserved for self-loop
}

__global__ void k_count(const int* __restrict__ ei, int* cnt) {
    int e = blockIdx.x * blockDim.x + threadIdx.x;
    if (e < N_EDGES) atomicAdd(&cnt[ei[N_EDGES + e]], 1);
}

__global__ void k_scan(const int* __restrict__ cnt, int* row_ptr) {
    __shared__ int sh[1024];
    __shared__ int carry_sh;
    if (threadIdx.x == 0) { carry_sh = 0; row_ptr[0] = 0; }
    __syncthreads();
    for (int base = 0; base < N_NODES; base += 1024) {
        int i = base + (int)threadIdx.x;
        int v = (i < N_NODES) ? cnt[i] : 0;
        sh[threadIdx.x] = v;
        __syncthreads();
        for (int off = 1; off < 1024; off <<= 1) {
            int t = (threadIdx.x >= (unsigned)off) ? sh[threadIdx.x - off] : 0;
            __syncthreads();
            sh[threadIdx.x] += t;
            __syncthreads();
        }
        int inc = sh[threadIdx.x] + carry_sh;
        if (i < N_NODES) row_ptr[i + 1] = inc;
        __syncthreads();
        if (threadIdx.x == 1023) carry_sh = inc;
        __syncthreads();
    }
}

__global__ void k_self(const int* __restrict__ row_ptr, int* colb) {
    int n = blockIdx.x * blockDim.x + threadIdx.x;
    if (n < N_NODES) colb[row_ptr[n]] = n;
}

__global__ void k_scatter(const int* __restrict__ ei, const int* __restrict__ row_ptr,
                          int* off, int* colb) {
    int e = blockIdx.x * blockDim.x + threadIdx.x;
    if (e < N_EDGES) {
        int dst = ei[N_EDGES + e];
        int p = atomicAdd(&off[dst], 1);
        colb[row_ptr[dst] + p] = ei[e];
    }
}

// ---------------- f32 -> bf16 convert (vector) ----------------
__global__ void k_cvt(const float* __restrict__ in, ushort* __restrict__ out, int n4) {
    int i = blockIdx.x * blockDim.x + threadIdx.x;
    if (i < n4) {
        float4 v = reinterpret_cast<const float4*>(in)[i];
        ushort4 o;
        o.x = f2bf(v.x); o.y = f2bf(v.y); o.z = f2bf(v.z); o.w = f2bf(v.w);
        reinterpret_cast<ushort4*>(out)[i] = o;
    }
}

// ---------------- W[K][N] -> Wt[N][K] bf16 transpose-convert ----------------
__global__ void k_wt(const float* __restrict__ W, ushort* __restrict__ Wt, int K, int N) {
    int idx = blockIdx.x * blockDim.x + threadIdx.x;
    if (idx < K * N) {
        int n = idx / K, k = idx - n * K;
        Wt[idx] = f2bf(W[(size_t)k * N + n]);
    }
}

// ---------------- bf16 MFMA GEMM: Cb[M,N] = bf16(A[M,K] @ Bt[N,K]^T) ----------------
// 128x128 tile, 4 waves (2x2), BK=32, global_load_lds staging (m97 structure).
__global__ __launch_bounds__(256) void k_gemm_bf16(const ushort* __restrict__ A,
                                                   const ushort* __restrict__ Bt,
                                                   ushort* __restrict__ Cb,
                                                   int M, int K, int N) {
    __shared__ __align__(16) ushort As[128 * 32];
    __shared__ __align__(16) ushort Bs[128 * 32];
    const int tid = threadIdx.x;
    const int wid = tid >> 6, lane = tid & 63;
    const int wm = wid >> 1, wn = wid & 1;
    const int row0 = blockIdx.x * 128, col0 = blockIdx.y * 128;

    const int c0 = wid * 2;
    const int sub = lane >> 2;        // 0..15: row within chunk
    const int kcol = (lane & 3) * 8;  // element column within 32-wide K slab

    int ar0 = row0 + c0 * 16 + sub;      if (ar0 > M - 1) ar0 = M - 1;
    int ar1 = row0 + c0 * 16 + 16 + sub; if (ar1 > M - 1) ar1 = M - 1;
    const size_t gA0 = (size_t)ar0 * K + kcol;
    const size_t gA1 = (size_t)ar1 * K + kcol;
    const size_t gB0 = (size_t)(col0 + c0 * 16 + sub) * K + kcol;
    const size_t gB1 = gB0 + (size_t)16 * K;
    ushort* lA0 = As + c0 * 512;
    ushort* lA1 = lA0 + 512;
    ushort* lB0 = Bs + c0 * 512;
    ushort* lB1 = lB0 + 512;

    const int afr = (wm * 64 + (lane & 15)) * 32 + (lane >> 4) * 8;
    const int bfr = (wn * 64 + (lane & 15)) * 32 + (lane >> 4) * 8;

    f32x4 acc[4][4] = {};

    for (int k0 = 0; k0 < K; k0 += 32) {
        __builtin_amdgcn_global_load_lds(
            (const __attribute__((address_space(1))) unsigned*)(A + gA0 + k0),
            (__attribute__((address_space(3))) unsigned*)lA0, 16, 0, 0);
        __builtin_amdgcn_global_load_lds(
            (const __attribute__((address_space(1))) unsigned*)(A + gA1 + k0),
            (__attribute__((address_space(3))) unsigned*)lA1, 16, 0, 0);
        __builtin_amdgcn_global_load_lds(
            (const __attribute__((address_space(1))) unsigned*)(Bt + gB0 + k0),
            (__attribute__((address_space(3))) unsigned*)lB0, 16, 0, 0);
        __builtin_amdgcn_global_load_lds(
            (const __attribute__((address_space(1))) unsigned*)(Bt + gB1 + k0),
            (__attribute__((address_space(3))) unsigned*)lB1, 16, 0, 0);
        __syncthreads();

        bf16x8 af[4], bg[4];
#pragma unroll
        for (int m = 0; m < 4; ++m)
            af[m] = *reinterpret_cast<const bf16x8*>(&As[afr + m * 16 * 32]);
#pragma unroll
        for (int n = 0; n < 4; ++n)
            bg[n] = *reinterpret_cast<const bf16x8*>(&Bs[bfr + n * 16 * 32]);
#pragma unroll
        for (int m = 0; m < 4; ++m)
#pragma unroll
            for (int n = 0; n < 4; ++n)
                acc[m][n] = __builtin_amdgcn_mfma_f32_16x16x32_bf16(af[m], bg[n], acc[m][n], 0, 0, 0);
        __syncthreads();
    }

    const int crow = row0 + wm * 64 + (lane >> 4) * 4;
    const int ccol = col0 + wn * 64 + (lane & 15);
#pragma unroll
    for (int m = 0; m < 4; ++m) {
#pragma unroll
        for (int j = 0; j < 4; ++j) {
            int r = crow + m * 16 + j;
            if (r < M) {
#pragma unroll
                for (int n = 0; n < 4; ++n)
                    Cb[(size_t)r * N + ccol + n * 16] = f2bf(acc[m][n][j]);
            }
        }
    }
}

// ---------------- per-(node,head) attention scores (bf16 xp) ----------------
template <int H>
__global__ void k_scores(const ushort* __restrict__ xpb, const float* __restrict__ asrc,
                         const float* __restrict__ adst, float* __restrict__ es,
                         float* __restrict__ ed) {
    const int n = blockIdx.x;
    const int w = threadIdx.x >> 6;  // head
    const int lane = threadIdx.x & 63;
    const ushort* xr = xpb + (size_t)n * H * 128 + w * 128;
    ushort2 v = *reinterpret_cast<const ushort2*>(&xr[2 * lane]);
    float v0 = bf2f(v.x), v1 = bf2f(v.y);
    float ps = v0 * asrc[w * 128 + 2 * lane] + v1 * asrc[w * 128 + 2 * lane + 1];
    float pd = v0 * adst[w * 128 + 2 * lane] + v1 * adst[w * 128 + 2 * lane + 1];
#pragma unroll
    for (int o = 32; o > 0; o >>= 1) {
        ps += __shfl_down(ps, o);
        pd += __shfl_down(pd, o);
    }
    if (lane == 0) { es[n * H + w] = ps; ed[n * H + w] = pd; }
}

// ---------------- per-node softmax aggregation + bias + BN + ReLU ----------------
// Each thread owns CPT contiguous channels; gather via ushort4/ushort2 (bf16 xp).
template <int H, int BLK, bool BF16OUT>
__global__ __launch_bounds__(BLK) void k_agg(
    const ushort* __restrict__ xpb, const float* __restrict__ es, const float* __restrict__ ed,
    const int* __restrict__ row_ptr, const int* __restrict__ colb,
    const float* __restrict__ bias, const float* __restrict__ gg, const float* __restrict__ be,
    const float* __restrict__ mu, const float* __restrict__ var, void* __restrict__ outv) {
    constexpr int HC = H * 128;
    constexpr int CPT = HC / BLK;  // 4 (H=4,BLK=128) or 2 (H=1,BLK=64)
    constexpr int CHUNK = 128;
    __shared__ int s_src[CHUNK];
    __shared__ float s_w[CHUNK][H];
    __shared__ float s_scale[H];
    __shared__ float s_sum[H];
    const int n = blockIdx.x;
    const int tid = threadIdx.x;
    const int beg = row_ptr[n], end = row_ptr[n + 1];
    const int ch0 = tid * CPT;
    const int h = ch0 / 128;
    float acc[CPT];
#pragma unroll
    for (int j = 0; j < CPT; ++j) acc[j] = 0.f;
    float m_run = -INFINITY, s_run = 0.f;  // live only in tid < H
    for (int cbeg = beg; cbeg < end; cbeg += CHUNK) {
        const int cnt = min(end - cbeg, CHUNK);
        for (int i = tid; i < cnt; i += BLK) {
            int src = colb[cbeg + i];
            s_src[i] = src;
#pragma unroll
            for (int hh = 0; hh < H; ++hh) {
                float e = es[src * H + hh] + ed[n * H + hh];
                s_w[i][hh] = (e > 0.f) ? e : NEG_SLOPE * e;
            }
        }
        __syncthreads();
        if (tid < H) {
            const int hh = tid;
            float cm = -INFINITY;
            for (int i = 0; i < cnt; ++i) cm = fmaxf(cm, s_w[i][hh]);
            float m_new = fmaxf(m_run, cm);
            float scale = __expf(m_run - m_new);
            float s = s_run * scale;
            for (int i = 0; i < cnt; ++i) {
                float w = __expf(s_w[i][hh] - m_new);
                s_w[i][hh] = w;
                s += w;
            }
            s_run = s; m_run = m_new;
            s_scale[hh] = scale;
            s_sum[hh] = s;
        }
        __syncthreads();
        {
            float sc = s_scale[h];
#pragma unroll
            for (int j = 0; j < CPT; ++j) acc[j] *= sc;
            for (int i = 0; i < cnt; ++i) {
                float w = s_w[i][h];
                const ushort* src_row = xpb + (size_t)s_src[i] * HC + ch0;
                if (CPT == 4) {
                    ushort4 v = *reinterpret_cast<const ushort4*>(src_row);
                    acc[0] = fmaf(w, bf2f(v.x), acc[0]);
                    acc[1] = fmaf(w, bf2f(v.y), acc[1]);
                    acc[2] = fmaf(w, bf2f(v.z), acc[2]);
                    acc[3 % CPT] = fmaf(w, bf2f(v.w), acc[3 % CPT]);
                } else {
                    ushort2 v = *reinterpret_cast<const ushort2*>(src_row);
                    acc[0] = fmaf(w, bf2f(v.x), acc[0]);
                    acc[1 % CPT] = fmaf(w, bf2f(v.y), acc[1 % CPT]);
                }
            }
        }
        __syncthreads();
    }
    float inv = 1.f / (s_sum[h] + 1e-16f);
#pragma unroll
    for (int j = 0; j < CPT; ++j) {
        int ch = ch0 + j;
        float val = acc[j] * inv + bias[ch];
        float sc = gg[ch] * rsqrtf(var[ch] + BN_EPS);
        val = (val - mu[ch]) * sc + be[ch];
        val = fmaxf(val, 0.f);
        if (BF16OUT)
            ((ushort*)outv)[(size_t)n * HC + ch] = f2bf(val);
        else
            ((float*)outv)[(size_t)n * HC + ch] = val;
    }
}

// ---------------- classifier head + softmax ----------------
__global__ __launch_bounds__(64) void k_cls(const float* __restrict__ Eg,
                                            const float* __restrict__ Wc1,
                                            const float* __restrict__ bc1,
                                            const float* __restrict__ Wc2,
                                            const float* __restrict__ bc2,
                                            float* __restrict__ P) {
    __shared__ float e_sh[128];
    __shared__ float h_sh[64];
    __shared__ float l_sh[10];
    const int n = blockIdx.x;
    const int t = threadIdx.x;
    e_sh[t] = Eg[(size_t)n * 128 + t];
    e_sh[t + 64] = Eg[(size_t)n * 128 + 64 + t];
    __syncthreads();
    float a = bc1[t];
#pragma unroll 4
    for (int k = 0; k < 128; ++k) a = fmaf(e_sh[k], Wc1[k * 64 + t], a);
    h_sh[t] = fmaxf(a, 0.f);
    __syncthreads();
    if (t < 10) {
        float b = bc2[t];
#pragma unroll 8
        for (int k = 0; k < 64; ++k) b = fmaf(h_sh[k], Wc2[k * 10 + t], b);
        l_sh[t] = b;
    }
    __syncthreads();
    if (t == 0) {
        float mx = l_sh[0];
        for (int j = 1; j < 10; ++j) mx = fmaxf(mx, l_sh[j]);
        float s = 0.f;
        float ex[10];
        for (int j = 0; j < 10; ++j) { ex[j] = __expf(l_sh[j] - mx); s += ex[j]; }
        float inv = 1.f / s;
        for (int j = 0; j < 10; ++j) P[(size_t)n * 10 + j] = ex[j] * inv;
    }
}

extern "C" void kernel_launch(void* const* d_in, const int* in_sizes, int n_in,
                              void* d_out, int out_size, void* d_ws, size_t ws_size,
                              hipStream_t stream) {
    const float* x     = (const float*)d_in[0];
    const int*   ei    = (const int*)d_in[1];
    const float* W1    = (const float*)d_in[2];
    const float* asrc1 = (const float*)d_in[3];
    const float* adst1 = (const float*)d_in[4];
    const float* b1    = (const float*)d_in[5];
    const float* gg1   = (const float*)d_in[6];
    const float* be1   = (const float*)d_in[7];
    const float* mu1   = (const float*)d_in[8];
    const float* v1    = (const float*)d_in[9];
    const float* W2    = (const float*)d_in[10];
    const float* asrc2 = (const float*)d_in[11];
    const float* adst2 = (const float*)d_in[12];
    const float* b2    = (const float*)d_in[13];
    const float* gg2   = (const float*)d_in[14];
    const float* be2   = (const float*)d_in[15];
    const float* mu2   = (const float*)d_in[16];
    const float* v2    = (const float*)d_in[17];
    const float* W3    = (const float*)d_in[18];
    const float* asrc3 = (const float*)d_in[19];
    const float* adst3 = (const float*)d_in[20];
    const float* b3    = (const float*)d_in[21];
    const float* gg3   = (const float*)d_in[22];
    const float* be3   = (const float*)d_in[23];
    const float* mu3   = (const float*)d_in[24];
    const float* v3    = (const float*)d_in[25];
    const float* Wc1   = (const float*)d_in[26];
    const float* bc1   = (const float*)d_in[27];
    const float* Wc2   = (const float*)d_in[28];
    const float* bc2   = (const float*)d_in[29];

    // ---- workspace layout (~107 MB) ----
    ushort* xpb  = (ushort*)d_ws;                      // bf16 xp, N*512
    ushort* hh   = xpb + (size_t)N_NODES * 512;        // bf16 GEMM input, N*512
    ushort* wt1  = hh + (size_t)N_NODES * 512;         // 512*256
    ushort* wt2  = wt1 + 512 * 256;                    // 512*512
    ushort* wt3  = wt2 + 512 * 512;                    // 128*512
    float*  es   = (float*)(wt3 + 128 * 512);
    float*  ed   = es + (size_t)N_NODES * 4;
    int* cnt     = (int*)(ed + (size_t)N_NODES * 4);
    int* off     = cnt + N_NODES;
    int* row_ptr = off + N_NODES;
    int* colb    = row_ptr + N_NODES + 4;

    float* Egnn = (float*)d_out;
    float* P    = Egnn + (size_t)N_NODES * 128;

    // ---- CSR build ----
    k_init<<<(N_NODES + 255) / 256, 256, 0, stream>>>(cnt, off);
    k_count<<<(N_EDGES + 255) / 256, 256, 0, stream>>>(ei, cnt);
    k_scan<<<1, 1024, 0, stream>>>(cnt, row_ptr);
    k_self<<<(N_NODES + 255) / 256, 256, 0, stream>>>(row_ptr, colb);
    k_scatter<<<(N_EDGES + 255) / 256, 256, 0, stream>>>(ei, row_ptr, off, colb);

    // ---- weight transpose-converts + x convert ----
    k_wt<<<(512 * 256 + 255) / 256, 256, 0, stream>>>(W1, wt1, 256, 512);
    k_wt<<<(512 * 512 + 255) / 256, 256, 0, stream>>>(W2, wt2, 512, 512);
    k_wt<<<(128 * 512 + 255) / 256, 256, 0, stream>>>(W3, wt3, 512, 128);
    {
        int n4 = N_NODES * 256 / 4;
        k_cvt<<<(n4 + 255) / 256, 256, 0, stream>>>(x, hh, n4);
    }

    const int mt = (N_NODES + 127) / 128;  // 391

    // ---- layer 1: 256 -> 4x128 ----
    {
        dim3 grid(mt, 4);
        k_gemm_bf16<<<grid, 256, 0, stream>>>(hh, wt1, xpb, N_NODES, 256, 512);
    }
    k_scores<4><<<N_NODES, 256, 0, stream>>>(xpb, asrc1, adst1, es, ed);
    k_agg<4, 128, true><<<N_NODES, 128, 0, stream>>>(xpb, es, ed, row_ptr, colb,
                                                     b1, gg1, be1, mu1, v1, hh);
    // ---- layer 2: 512 -> 4x128 ----
    {
        dim3 grid(mt, 4);
        k_gemm_bf16<<<grid, 256, 0, stream>>>(hh, wt2, xpb, N_NODES, 512, 512);
    }
    k_scores<4><<<N_NODES, 256, 0, stream>>>(xpb, asrc2, adst2, es, ed);
    k_agg<4, 128, true><<<N_NODES, 128, 0, stream>>>(xpb, es, ed, row_ptr, colb,
                                                     b2, gg2, be2, mu2, v2, hh);
    // ---- layer 3: 512 -> 1x128 ----
    {
        dim3 grid(mt, 1);
        k_gemm_bf16<<<grid, 256, 0, stream>>>(hh, wt3, xpb, N_NODES, 512, 128);
    }
    k_scores<1><<<N_NODES, 64, 0, stream>>>(xpb, asrc3, adst3, es, ed);
    k_agg<1, 64, false><<<N_NODES, 64, 0, stream>>>(xpb, es, ed, row_ptr, colb,
                                                    b3, gg3, be3, mu3, v3, Egnn);
    // ---- classifier ----
    k_cls<<<N_NODES, 64, 0, stream>>>(Egnn, Wc1, bc1, Wc2, bc2, P);
}

// Round 4
// 563.511 us; speedup vs baseline: 2.4486x; 1.2119x over previous
//
#include <hip/hip_runtime.h>
#include <math.h>

#define N_NODES 50000
#define N_EDGES 200000
#define NEG_SLOPE 0.2f
#define BN_EPS 1e-5f

#define SCAN_ELEMS 1024
#define SCAN_NB ((N_NODES + SCAN_ELEMS - 1) / SCAN_ELEMS)  // 49

typedef __attribute__((ext_vector_type(4))) float f32x4;
typedef __attribute__((ext_vector_type(8))) short bf16x8;

__device__ __forceinline__ ushort f2bf(float x) {
    unsigned u = __float_as_uint(x);
    u += 0x7FFFu + ((u >> 16) & 1u);
    return (ushort)(u >> 16);
}
__device__ __forceinline__ float bf2f(ushort u) {
    return __uint_as_float(((unsigned)u) << 16);
}

// ---------------- CSR build ----------------
__global__ void k_init(int* cnt, int* off) {
    int i = blockIdx.x * blockDim.x + threadIdx.x;
    if (i < N_NODES) { cnt[i] = 1; off[i] = 1; }  // slot 0 reserved for self-loop
}

__global__ void k_count(const int* __restrict__ ei, int* cnt) {
    int e = blockIdx.x * blockDim.x + threadIdx.x;
    if (e < N_EDGES) atomicAdd(&cnt[ei[N_EDGES + e]], 1);
}

// hierarchical scan, phase 1: per-block (1024 elems) inclusive scan + partial
__global__ __launch_bounds__(256) void k_scan1(const int* __restrict__ cnt,
                                               int* __restrict__ incl,
                                               int* __restrict__ partials) {
    __shared__ int sh[256];
    const int t = threadIdx.x;
    const int base = blockIdx.x * SCAN_ELEMS + t * 4;
    int v0 = 0, v1 = 0, v2 = 0, v3 = 0;
    if (base + 3 < N_NODES) {
        int4 lv = *reinterpret_cast<const int4*>(&cnt[base]);
        v0 = lv.x; v1 = lv.y; v2 = lv.z; v3 = lv.w;
    } else {
        if (base + 0 < N_NODES) v0 = cnt[base + 0];
        if (base + 1 < N_NODES) v1 = cnt[base + 1];
        if (base + 2 < N_NODES) v2 = cnt[base + 2];
        if (base + 3 < N_NODES) v3 = cnt[base + 3];
    }
    const int s1 = v0 + v1, s2 = s1 + v2, s3 = s2 + v3;
    sh[t] = s3;
    __syncthreads();
#pragma unroll
    for (int off = 1; off < 256; off <<= 1) {
        int x = (t >= off) ? sh[t - off] : 0;
        __syncthreads();
        sh[t] += x;
        __syncthreads();
    }
    const int excl = sh[t] - s3;
    if (base + 0 < N_NODES) incl[base + 0] = excl + v0;
    if (base + 1 < N_NODES) incl[base + 1] = excl + s1;
    if (base + 2 < N_NODES) incl[base + 2] = excl + s2;
    if (base + 3 < N_NODES) incl[base + 3] = excl + s3;
    if (t == 255) partials[blockIdx.x] = sh[255];
}

// phase 2: exclusive scan of 49 partials (trivial)
__global__ void k_scan2(const int* __restrict__ partials, int* __restrict__ pofs) {
    if (threadIdx.x == 0) {
        int s = 0;
        for (int b = 0; b < SCAN_NB; ++b) { pofs[b] = s; s += partials[b]; }
    }
}

// phase 3: row_ptr[i+1] = incl[i] + pofs[i>>10]; row_ptr[0] = 0
__global__ void k_scan3(const int* __restrict__ incl, const int* __restrict__ pofs,
                        int* __restrict__ row_ptr) {
    int i = blockIdx.x * blockDim.x + threadIdx.x;
    if (i < N_NODES) row_ptr[i + 1] = incl[i] + pofs[i >> 10];
    if (i == 0) row_ptr[0] = 0;
}

__global__ void k_self(const int* __restrict__ row_ptr, int* colb) {
    int n = blockIdx.x * blockDim.x + threadIdx.x;
    if (n < N_NODES) colb[row_ptr[n]] = n;
}

__global__ void k_scatter(const int* __restrict__ ei, const int* __restrict__ row_ptr,
                          int* off, int* colb) {
    int e = blockIdx.x * blockDim.x + threadIdx.x;
    if (e < N_EDGES) {
        int dst = ei[N_EDGES + e];
        int p = atomicAdd(&off[dst], 1);
        colb[row_ptr[dst] + p] = ei[e];
    }
}

// ---------------- f32 -> bf16 convert (vector) ----------------
__global__ void k_cvt(const float* __restrict__ in, ushort* __restrict__ out, int n4) {
    int i = blockIdx.x * blockDim.x + threadIdx.x;
    if (i < n4) {
        float4 v = reinterpret_cast<const float4*>(in)[i];
        ushort4 o;
        o.x = f2bf(v.x); o.y = f2bf(v.y); o.z = f2bf(v.z); o.w = f2bf(v.w);
        reinterpret_cast<ushort4*>(out)[i] = o;
    }
}

// ---------------- W[K][N] -> Wt[N][K] bf16 transpose-convert ----------------
__global__ void k_wt(const float* __restrict__ W, ushort* __restrict__ Wt, int K, int N) {
    int idx = blockIdx.x * blockDim.x + threadIdx.x;
    if (idx < K * N) {
        int n = idx / K, k = idx - n * K;
        Wt[idx] = f2bf(W[(size_t)k * N + n]);
    }
}

// ---------------- bf16 MFMA GEMM: Cb[M,N] = bf16(A[M,K] @ Bt[N,K]^T) ----------------
__global__ __launch_bounds__(256) void k_gemm_bf16(const ushort* __restrict__ A,
                                                   const ushort* __restrict__ Bt,
                                                   ushort* __restrict__ Cb,
                                                   int M, int K, int N) {
    __shared__ __align__(16) ushort As[128 * 32];
    __shared__ __align__(16) ushort Bs[128 * 32];
    const int tid = threadIdx.x;
    const int wid = tid >> 6, lane = tid & 63;
    const int wm = wid >> 1, wn = wid & 1;
    const int row0 = blockIdx.x * 128, col0 = blockIdx.y * 128;

    const int c0 = wid * 2;
    const int sub = lane >> 2;
    const int kcol = (lane & 3) * 8;

    int ar0 = row0 + c0 * 16 + sub;      if (ar0 > M - 1) ar0 = M - 1;
    int ar1 = row0 + c0 * 16 + 16 + sub; if (ar1 > M - 1) ar1 = M - 1;
    const size_t gA0 = (size_t)ar0 * K + kcol;
    const size_t gA1 = (size_t)ar1 * K + kcol;
    const size_t gB0 = (size_t)(col0 + c0 * 16 + sub) * K + kcol;
    const size_t gB1 = gB0 + (size_t)16 * K;
    ushort* lA0 = As + c0 * 512;
    ushort* lA1 = lA0 + 512;
    ushort* lB0 = Bs + c0 * 512;
    ushort* lB1 = lB0 + 512;

    const int afr = (wm * 64 + (lane & 15)) * 32 + (lane >> 4) * 8;
    const int bfr = (wn * 64 + (lane & 15)) * 32 + (lane >> 4) * 8;

    f32x4 acc[4][4] = {};

    for (int k0 = 0; k0 < K; k0 += 32) {
        __builtin_amdgcn_global_load_lds(
            (const __attribute__((address_space(1))) unsigned*)(A + gA0 + k0),
            (__attribute__((address_space(3))) unsigned*)lA0, 16, 0, 0);
        __builtin_amdgcn_global_load_lds(
            (const __attribute__((address_space(1))) unsigned*)(A + gA1 + k0),
            (__attribute__((address_space(3))) unsigned*)lA1, 16, 0, 0);
        __builtin_amdgcn_global_load_lds(
            (const __attribute__((address_space(1))) unsigned*)(Bt + gB0 + k0),
            (__attribute__((address_space(3))) unsigned*)lB0, 16, 0, 0);
        __builtin_amdgcn_global_load_lds(
            (const __attribute__((address_space(1))) unsigned*)(Bt + gB1 + k0),
            (__attribute__((address_space(3))) unsigned*)lB1, 16, 0, 0);
        __syncthreads();

        bf16x8 af[4], bg[4];
#pragma unroll
        for (int m = 0; m < 4; ++m)
            af[m] = *reinterpret_cast<const bf16x8*>(&As[afr + m * 16 * 32]);
#pragma unroll
        for (int n = 0; n < 4; ++n)
            bg[n] = *reinterpret_cast<const bf16x8*>(&Bs[bfr + n * 16 * 32]);
#pragma unroll
        for (int m = 0; m < 4; ++m)
#pragma unroll
            for (int n = 0; n < 4; ++n)
                acc[m][n] = __builtin_amdgcn_mfma_f32_16x16x32_bf16(af[m], bg[n], acc[m][n], 0, 0, 0);
        __syncthreads();
    }

    const int crow = row0 + wm * 64 + (lane >> 4) * 4;
    const int ccol = col0 + wn * 64 + (lane & 15);
#pragma unroll
    for (int m = 0; m < 4; ++m) {
#pragma unroll
        for (int j = 0; j < 4; ++j) {
            int r = crow + m * 16 + j;
            if (r < M) {
#pragma unroll
                for (int n = 0; n < 4; ++n)
                    Cb[(size_t)r * N + ccol + n * 16] = f2bf(acc[m][n][j]);
            }
        }
    }
}

// ---------------- per-(node,head) attention scores (bf16 xp) ----------------
template <int H>
__global__ void k_scores(const ushort* __restrict__ xpb, const float* __restrict__ asrc,
                         const float* __restrict__ adst, float* __restrict__ es,
                         float* __restrict__ ed) {
    const int n = blockIdx.x;
    const int w = threadIdx.x >> 6;  // head
    const int lane = threadIdx.x & 63;
    const ushort* xr = xpb + (size_t)n * H * 128 + w * 128;
    ushort2 v = *reinterpret_cast<const ushort2*>(&xr[2 * lane]);
    float v0 = bf2f(v.x), v1 = bf2f(v.y);
    float ps = v0 * asrc[w * 128 + 2 * lane] + v1 * asrc[w * 128 + 2 * lane + 1];
    float pd = v0 * adst[w * 128 + 2 * lane] + v1 * adst[w * 128 + 2 * lane + 1];
#pragma unroll
    for (int o = 32; o > 0; o >>= 1) {
        ps += __shfl_down(ps, o);
        pd += __shfl_down(pd, o);
    }
    if (lane == 0) { es[n * H + w] = ps; ed[n * H + w] = pd; }
}

// ---------------- per-node softmax aggregation + bias + BN + ReLU ----------------
template <int H, int BLK, bool BF16OUT>
__global__ __launch_bounds__(BLK) void k_agg(
    const ushort* __restrict__ xpb, const float* __restrict__ es, const float* __restrict__ ed,
    const int* __restrict__ row_ptr, const int* __restrict__ colb,
    const float* __restrict__ bias, const float* __restrict__ gg, const float* __restrict__ be,
    const float* __restrict__ mu, const float* __restrict__ var, void* __restrict__ outv) {
    constexpr int HC = H * 128;
    constexpr int CPT = HC / BLK;  // 4 (H=4,BLK=128) or 2 (H=1,BLK=64)
    constexpr int CHUNK = 128;
    __shared__ int s_src[CHUNK];
    __shared__ float s_w[CHUNK][H];
    __shared__ float s_scale[H];
    __shared__ float s_sum[H];
    const int n = blockIdx.x;
    const int tid = threadIdx.x;
    const int beg = row_ptr[n], end = row_ptr[n + 1];
    const int ch0 = tid * CPT;
    const int h = ch0 / 128;
    float acc[CPT];
#pragma unroll
    for (int j = 0; j < CPT; ++j) acc[j] = 0.f;
    float m_run = -INFINITY, s_run = 0.f;
    for (int cbeg = beg; cbeg < end; cbeg += CHUNK) {
        const int cnt = min(end - cbeg, CHUNK);
        for (int i = tid; i < cnt; i += BLK) {
            int src = colb[cbeg + i];
            s_src[i] = src;
#pragma unroll
            for (int hh = 0; hh < H; ++hh) {
                float e = es[src * H + hh] + ed[n * H + hh];
                s_w[i][hh] = (e > 0.f) ? e : NEG_SLOPE * e;
            }
        }
        __syncthreads();
        if (tid < H) {
            const int hh = tid;
            float cm = -INFINITY;
            for (int i = 0; i < cnt; ++i) cm = fmaxf(cm, s_w[i][hh]);
            float m_new = fmaxf(m_run, cm);
            float scale = __expf(m_run - m_new);
            float s = s_run * scale;
            for (int i = 0; i < cnt; ++i) {
                float w = __expf(s_w[i][hh] - m_new);
                s_w[i][hh] = w;
                s += w;
            }
            s_run = s; m_run = m_new;
            s_scale[hh] = scale;
            s_sum[hh] = s;
        }
        __syncthreads();
        {
            float sc = s_scale[h];
#pragma unroll
            for (int j = 0; j < CPT; ++j) acc[j] *= sc;
            for (int i = 0; i < cnt; ++i) {
                float w = s_w[i][h];
                const ushort* src_row = xpb + (size_t)s_src[i] * HC + ch0;
                if (CPT == 4) {
                    ushort4 v = *reinterpret_cast<const ushort4*>(src_row);
                    acc[0] = fmaf(w, bf2f(v.x), acc[0]);
                    acc[1] = fmaf(w, bf2f(v.y), acc[1]);
                    acc[2] = fmaf(w, bf2f(v.z), acc[2]);
                    acc[3 % CPT] = fmaf(w, bf2f(v.w), acc[3 % CPT]);
                } else {
                    ushort2 v = *reinterpret_cast<const ushort2*>(src_row);
                    acc[0] = fmaf(w, bf2f(v.x), acc[0]);
                    acc[1 % CPT] = fmaf(w, bf2f(v.y), acc[1 % CPT]);
                }
            }
        }
        __syncthreads();
    }
    float inv = 1.f / (s_sum[h] + 1e-16f);
#pragma unroll
    for (int j = 0; j < CPT; ++j) {
        int ch = ch0 + j;
        float val = acc[j] * inv + bias[ch];
        float sc = gg[ch] * rsqrtf(var[ch] + BN_EPS);
        val = (val - mu[ch]) * sc + be[ch];
        val = fmaxf(val, 0.f);
        if (BF16OUT)
            ((ushort*)outv)[(size_t)n * HC + ch] = f2bf(val);
        else
            ((float*)outv)[(size_t)n * HC + ch] = val;
    }
}

// ---------------- classifier: LDS-staged, 16 nodes / 256-thread block ----------------
#define CLS_NB 16
__global__ __launch_bounds__(256) void k_cls(const float* __restrict__ Eg,
                                             const float* __restrict__ Wc1,
                                             const float* __restrict__ bc1,
                                             const float* __restrict__ Wc2,
                                             const float* __restrict__ bc2,
                                             float* __restrict__ P) {
    __shared__ float Ws[128 * 64];        // 32 KB
    __shared__ float W2s[64 * 10 + 16];   // Wc2 + bc2 stash
    __shared__ float b1s[64];
    __shared__ float e_sh[CLS_NB][128];   // 8 KB
    __shared__ float h_sh[CLS_NB][64];    // 4 KB
    __shared__ float l_sh[CLS_NB][10];
    const int t = threadIdx.x;
    const int n0 = blockIdx.x * CLS_NB;

    for (int i = t; i < 2048; i += 256)
        reinterpret_cast<float4*>(Ws)[i] = reinterpret_cast<const float4*>(Wc1)[i];
    for (int i = t; i < 640; i += 256) W2s[i] = Wc2[i];
    if (t < 64) b1s[t] = bc1[t];
    if (t >= 64 && t < 74) W2s[640 + t - 64] = bc2[t - 64];
    for (int i = t; i < CLS_NB * 32; i += 256) {
        int node = i >> 5, q = i & 31;
        reinterpret_cast<float4*>(&e_sh[node][0])[q] =
            reinterpret_cast<const float4*>(&Eg[(size_t)(n0 + node) * 128])[q];
    }
    __syncthreads();

    {
        const int c = t & 63, ng = t >> 6;  // 4 node-groups x 64 channels
        float acc0 = b1s[c], acc1 = b1s[c], acc2 = b1s[c], acc3 = b1s[c];
        for (int k = 0; k < 128; ++k) {
            float w = Ws[k * 64 + c];
            acc0 = fmaf(e_sh[ng * 4 + 0][k], w, acc0);
            acc1 = fmaf(e_sh[ng * 4 + 1][k], w, acc1);
            acc2 = fmaf(e_sh[ng * 4 + 2][k], w, acc2);
            acc3 = fmaf(e_sh[ng * 4 + 3][k], w, acc3);
        }
        h_sh[ng * 4 + 0][c] = fmaxf(acc0, 0.f);
        h_sh[ng * 4 + 1][c] = fmaxf(acc1, 0.f);
        h_sh[ng * 4 + 2][c] = fmaxf(acc2, 0.f);
        h_sh[ng * 4 + 3][c] = fmaxf(acc3, 0.f);
    }
    __syncthreads();
    if (t < CLS_NB * 10) {
        int node = t / 10, c = t - node * 10;
        float acc = W2s[640 + c];
        for (int k = 0; k < 64; ++k) acc = fmaf(h_sh[node][k], W2s[k * 10 + c], acc);
        l_sh[node][c] = acc;
    }
    __syncthreads();
    if (t < CLS_NB) {
        float mx = l_sh[t][0];
        for (int j = 1; j < 10; ++j) mx = fmaxf(mx, l_sh[t][j]);
        float s = 0.f;
        float ex[10];
        for (int j = 0; j < 10; ++j) { ex[j] = __expf(l_sh[t][j] - mx); s += ex[j]; }
        float inv = 1.f / s;
        for (int j = 0; j < 10; ++j) l_sh[t][j] = ex[j] * inv;
    }
    __syncthreads();
    if (t < CLS_NB * 10) {
        int node = t / 10, c = t - node * 10;
        P[(size_t)(n0 + node) * 10 + c] = l_sh[node][c];
    }
}

extern "C" void kernel_launch(void* const* d_in, const int* in_sizes, int n_in,
                              void* d_out, int out_size, void* d_ws, size_t ws_size,
                              hipStream_t stream) {
    const float* x     = (const float*)d_in[0];
    const int*   ei    = (const int*)d_in[1];
    const float* W1    = (const float*)d_in[2];
    const float* asrc1 = (const float*)d_in[3];
    const float* adst1 = (const float*)d_in[4];
    const float* b1    = (const float*)d_in[5];
    const float* gg1   = (const float*)d_in[6];
    const float* be1   = (const float*)d_in[7];
    const float* mu1   = (const float*)d_in[8];
    const float* v1    = (const float*)d_in[9];
    const float* W2    = (const float*)d_in[10];
    const float* asrc2 = (const float*)d_in[11];
    const float* adst2 = (const float*)d_in[12];
    const float* b2    = (const float*)d_in[13];
    const float* gg2   = (const float*)d_in[14];
    const float* be2   = (const float*)d_in[15];
    const float* mu2   = (const float*)d_in[16];
    const float* v2    = (const float*)d_in[17];
    const float* W3    = (const float*)d_in[18];
    const float* asrc3 = (const float*)d_in[19];
    const float* adst3 = (const float*)d_in[20];
    const float* b3    = (const float*)d_in[21];
    const float* gg3   = (const float*)d_in[22];
    const float* be3   = (const float*)d_in[23];
    const float* mu3   = (const float*)d_in[24];
    const float* v3    = (const float*)d_in[25];
    const float* Wc1   = (const float*)d_in[26];
    const float* bc1   = (const float*)d_in[27];
    const float* Wc2   = (const float*)d_in[28];
    const float* bc2   = (const float*)d_in[29];

    // ---- workspace layout (~107 MB) ----
    ushort* xpb  = (ushort*)d_ws;                      // bf16 xp, N*512
    ushort* hh   = xpb + (size_t)N_NODES * 512;        // bf16 GEMM input, N*512
    ushort* wt1  = hh + (size_t)N_NODES * 512;         // 512*256
    ushort* wt2  = wt1 + 512 * 256;                    // 512*512
    ushort* wt3  = wt2 + 512 * 512;                    // 128*512
    float*  es   = (float*)(wt3 + 128 * 512);
    float*  ed   = es + (size_t)N_NODES * 4;
    int* cnt     = (int*)(ed + (size_t)N_NODES * 4);
    int* off     = cnt + N_NODES;
    int* row_ptr = off + N_NODES;
    int* colb    = row_ptr + N_NODES + 4;
    int* incl    = colb + N_EDGES + N_NODES;
    int* partials = incl + N_NODES;
    int* pofs    = partials + SCAN_NB;

    float* Egnn = (float*)d_out;
    float* P    = Egnn + (size_t)N_NODES * 128;

    // ---- CSR build ----
    k_init<<<(N_NODES + 255) / 256, 256, 0, stream>>>(cnt, off);
    k_count<<<(N_EDGES + 255) / 256, 256, 0, stream>>>(ei, cnt);
    k_scan1<<<SCAN_NB, 256, 0, stream>>>(cnt, incl, partials);
    k_scan2<<<1, 64, 0, stream>>>(partials, pofs);
    k_scan3<<<(N_NODES + 255) / 256, 256, 0, stream>>>(incl, pofs, row_ptr);
    k_self<<<(N_NODES + 255) / 256, 256, 0, stream>>>(row_ptr, colb);
    k_scatter<<<(N_EDGES + 255) / 256, 256, 0, stream>>>(ei, row_ptr, off, colb);

    // ---- weight transpose-converts + x convert ----
    k_wt<<<(512 * 256 + 255) / 256, 256, 0, stream>>>(W1, wt1, 256, 512);
    k_wt<<<(512 * 512 + 255) / 256, 256, 0, stream>>>(W2, wt2, 512, 512);
    k_wt<<<(128 * 512 + 255) / 256, 256, 0, stream>>>(W3, wt3, 512, 128);
    {
        int n4 = N_NODES * 256 / 4;
        k_cvt<<<(n4 + 255) / 256, 256, 0, stream>>>(x, hh, n4);
    }

    const int mt = (N_NODES + 127) / 128;  // 391

    // ---- layer 1: 256 -> 4x128 ----
    {
        dim3 grid(mt, 4);
        k_gemm_bf16<<<grid, 256, 0, stream>>>(hh, wt1, xpb, N_NODES, 256, 512);
    }
    k_scores<4><<<N_NODES, 256, 0, stream>>>(xpb, asrc1, adst1, es, ed);
    k_agg<4, 128, true><<<N_NODES, 128, 0, stream>>>(xpb, es, ed, row_ptr, colb,
                                                     b1, gg1, be1, mu1, v1, hh);
    // ---- layer 2: 512 -> 4x128 ----
    {
        dim3 grid(mt, 4);
        k_gemm_bf16<<<grid, 256, 0, stream>>>(hh, wt2, xpb, N_NODES, 512, 512);
    }
    k_scores<4><<<N_NODES, 256, 0, stream>>>(xpb, asrc2, adst2, es, ed);
    k_agg<4, 128, true><<<N_NODES, 128, 0, stream>>>(xpb, es, ed, row_ptr, colb,
                                                     b2, gg2, be2, mu2, v2, hh);
    // ---- layer 3: 512 -> 1x128 ----
    {
        dim3 grid(mt, 1);
        k_gemm_bf16<<<grid, 256, 0, stream>>>(hh, wt3, xpb, N_NODES, 512, 128);
    }
    k_scores<1><<<N_NODES, 64, 0, stream>>>(xpb, asrc3, adst3, es, ed);
    k_agg<1, 64, false><<<N_NODES, 64, 0, stream>>>(xpb, es, ed, row_ptr, colb,
                                                    b3, gg3, be3, mu3, v3, Egnn);
    // ---- classifier ----
    k_cls<<<(N_NODES + CLS_NB - 1) / CLS_NB, 256, 0, stream>>>(Egnn, Wc1, bc1, Wc2, bc2, P);
}